// Round 15
// baseline (169.718 us; speedup 1.0000x reference)
//
#include <hip/hip_runtime.h>
#include <hip/hip_bf16.h>
#include <math.h>

#define N_NODES 50000
#define N_EDGES 800000
#define EE_TOTAL (N_EDGES + N_NODES)
#define CAP 64  // bucket capacity; in-degree ~ Binomial(800K, 1/50K), P(>64) ~ 1e-13

#define GEMM1_BLOCKS ((N_NODES + 63) / 64)      // 782
#define SCAT_BLOCKS ((EE_TOTAL + 1023) / 1024)  // 831 (1024 edges/block, 4/thread)
#define FUSED_BLOCKS (GEMM1_BLOCKS + SCAT_BLOCKS)
#define AGG1_BLOCKS 25000  // 3125 node-groups x 8 (head,chhalf); bid%8 -> XCD slice

typedef __attribute__((ext_vector_type(8))) short bf16x8;
typedef __attribute__((ext_vector_type(4))) float f32x4;

__device__ __forceinline__ float bf2f(unsigned short s) {
  return __uint_as_float((unsigned)s << 16);
}
__device__ __forceinline__ unsigned short f2bf(float f) {
  unsigned u = __float_as_uint(f);
  return (unsigned short)((u + 0x7FFFu + ((u >> 16) & 1u)) >> 16);  // RNE
}
__device__ __forceinline__ float lrelu(float e) { return e > 0.f ? e : 0.2f * e; }

// ---------------------------------------------------------------- prep
__global__ void prep_kernel(const float* __restrict__ W1, const float* __restrict__ W2,
                            unsigned short* __restrict__ W1t, unsigned short* __restrict__ W2t,
                            int* __restrict__ counts) {
  int i = blockIdx.x * blockDim.x + threadIdx.x;
  if (i < N_NODES) counts[i] = 0;
  if (i < 256 * 128) W1t[i] = f2bf(W1[(i & 127) * 256 + (i >> 7)]);
  if (i < 64 * 256) W2t[i] = f2bf(W2[(i & 255) * 64 + (i >> 8)]);
}

// ---------------------------------------------------------------- fused scatter + GEMM1
__device__ __forceinline__ void scatter_body(int sid, int t,
                                             const int* __restrict__ src,
                                             const int* __restrict__ dst,
                                             int* __restrict__ counts,
                                             unsigned short* __restrict__ col) {
  int base = sid * 1024 + t * 4;
  int ss[4], dd[4];
#pragma unroll
  for (int k = 0; k < 4; ++k) {
    int i = base + k;
    if (i < N_EDGES) { ss[k] = src[i]; dd[k] = dst[i]; }
    else if (i < EE_TOTAL) { ss[k] = i - N_EDGES; dd[k] = ss[k]; }
    else { ss[k] = 0; dd[k] = -1; }
  }
#pragma unroll
  for (int k = 0; k < 4; ++k) {
    if (dd[k] >= 0) {
      int pos = atomicAdd(&counts[dd[k]], 1);
      if (pos < CAP) col[(size_t)dd[k] * CAP + pos] = (unsigned short)ss[k];
    }
  }
}

// gemm1 writes h1t[8][M][32] (head-chhalf-major) so each (head,chhalf) slice is a
// contiguous 3.2 MB block -> L2-resident per XCD in agg1. alpha out transposed.
__global__ __launch_bounds__(256) void fused_kernel(const int* __restrict__ src,
                                                    const int* __restrict__ dst,
                                                    int* __restrict__ counts,
                                                    unsigned short* __restrict__ col,
                                                    const float* __restrict__ A,           // x [M][128] f32
                                                    const unsigned short* __restrict__ Bt, // W1t [256][128]
                                                    unsigned short* __restrict__ h1t,      // [8][M][32]
                                                    const float* __restrict__ att_s,
                                                    const float* __restrict__ att_d,
                                                    float* __restrict__ as_out,            // as_t [4][M]
                                                    float* __restrict__ ad_out) {          // ad_t [4][M]
  __shared__ unsigned short Bs[256 * 128];  // 64KB, XOR-swizzled (gemm blocks only)
  int b = blockIdx.x;
  int t = threadIdx.x;
  bool is_gemm;
  int id;
  if (b < 2 * GEMM1_BLOCKS) { is_gemm = (b & 1) == 0; id = b >> 1; }
  else { is_gemm = false; id = b - GEMM1_BLOCKS; }

  if (!is_gemm) {
    scatter_body(id, t, src, dst, counts, col);
    return;
  }

  const int M = N_NODES;
  int lane = t & 63, w = t >> 6;
  int row0 = id * 64;
#pragma unroll
  for (int i = 0; i < 16; ++i) {
    int idx = i * 256 + t;
    int n = idx >> 4;
    uint4 v = ((const uint4*)Bt)[idx];
    int byte = (idx * 16) ^ ((n & 7) << 4);
    *(uint4*)((char*)Bs + byte) = v;
  }
  __syncthreads();
  int rl = lane & 15, kg = lane >> 4;
  f32x4 acc[4][4] = {};
  for (int ks = 0; ks < 4; ++ks) {
    bf16x8 af[4], bfr[4];
#pragma unroll
    for (int rb = 0; rb < 4; ++rb) {
      int row = row0 + rb * 16 + rl;
      float4 v0 = make_float4(0.f, 0.f, 0.f, 0.f), v1 = v0;
      if (row < M) {
        const float* p = A + (size_t)row * 128 + ks * 32 + kg * 8;
        v0 = *(const float4*)p;
        v1 = *(const float4*)(p + 4);
      }
      bf16x8 a;
      a[0] = (short)f2bf(v0.x); a[1] = (short)f2bf(v0.y);
      a[2] = (short)f2bf(v0.z); a[3] = (short)f2bf(v0.w);
      a[4] = (short)f2bf(v1.x); a[5] = (short)f2bf(v1.y);
      a[6] = (short)f2bf(v1.z); a[7] = (short)f2bf(v1.w);
      af[rb] = a;
    }
#pragma unroll
    for (int cb = 0; cb < 4; ++cb) {
      int n = w * 64 + cb * 16 + rl;
      int byte = (n * 256 + ks * 64 + kg * 16) ^ ((n & 7) << 4);
      bfr[cb] = *(const bf16x8*)((char*)Bs + byte);
    }
#pragma unroll
    for (int rb = 0; rb < 4; ++rb)
#pragma unroll
      for (int cb = 0; cb < 4; ++cb)
        acc[rb][cb] = __builtin_amdgcn_mfma_f32_16x16x32_bf16(af[rb], bfr[cb], acc[rb][cb], 0, 0, 0);
  }
  float asv[4], adv[4];
#pragma unroll
  for (int cb = 0; cb < 4; ++cb) {
    int c = w * 64 + cb * 16 + rl;
    asv[cb] = att_s[c];
    adv[cb] = att_d[c];
  }
#pragma unroll
  for (int rb = 0; rb < 4; ++rb) {
#pragma unroll
    for (int r = 0; r < 4; ++r) {
      int row = row0 + rb * 16 + kg * 4 + r;
      bool ok = row < M;
      float sp = 0.f, dp = 0.f;
#pragma unroll
      for (int cb = 0; cb < 4; ++cb) {
        float v = acc[rb][cb][r];
        if (ok) {
          // head = w, chhalf = cb>>1, ch-in-half = (cb&1)*16 + rl
          size_t hc = (size_t)(w * 2 + (cb >> 1));
          h1t[(hc * M + row) * 32 + (cb & 1) * 16 + rl] = f2bf(v);
        }
        sp += v * asv[cb];
        dp += v * adv[cb];
      }
#pragma unroll
      for (int off = 1; off < 16; off <<= 1) {
        sp += __shfl_xor(sp, off, 64);
        dp += __shfl_xor(dp, off, 64);
      }
      if (ok && rl == 0) {
        as_out[w * M + row] = sp;  // transposed: head-major
        ad_out[w * M + row] = dp;
      }
    }
  }
}

// ---------------------------------------------------------------- GEMM2 (MFMA, LDS-staged)
__global__ __launch_bounds__(256) void gemm2_kernel(const unsigned short* __restrict__ A,   // x2b [M][256]
                                                    const unsigned short* __restrict__ Bt,  // [64][256]
                                                    unsigned short* __restrict__ Cb,        // [M][64]
                                                    const float* __restrict__ att_s,
                                                    const float* __restrict__ att_d,
                                                    float* __restrict__ as_out,             // [M]
                                                    float* __restrict__ ad_out) {
  __shared__ unsigned short Bs[64 * 256];  // 32KB
  const int M = N_NODES;
  int t = threadIdx.x;
  int lane = t & 63, w = t >> 6;
  int row0 = blockIdx.x * 64;
#pragma unroll
  for (int i = 0; i < 8; ++i) {
    int idx = i * 256 + t;
    int n = idx >> 5;
    uint4 v = ((const uint4*)Bt)[idx];
    int byte = (idx * 16) ^ ((n & 7) << 4);
    *(uint4*)((char*)Bs + byte) = v;
  }
  __syncthreads();
  int rl = lane & 15, kg = lane >> 4;
  int arow = row0 + w * 16 + rl;
  f32x4 acc[4] = {};
  for (int ks = 0; ks < 8; ++ks) {
    bf16x8 a = {};
    if (arow < M) a = *(const bf16x8*)(A + (size_t)arow * 256 + ks * 32 + kg * 8);
#pragma unroll
    for (int cb = 0; cb < 4; ++cb) {
      int n = cb * 16 + rl;
      int byte = (n * 512 + ks * 64 + kg * 16) ^ ((n & 7) << 4);
      bf16x8 bfrag = *(const bf16x8*)((char*)Bs + byte);
      acc[cb] = __builtin_amdgcn_mfma_f32_16x16x32_bf16(a, bfrag, acc[cb], 0, 0, 0);
    }
  }
  float asv[4], adv[4];
#pragma unroll
  for (int cb = 0; cb < 4; ++cb) {
    int c = cb * 16 + rl;
    asv[cb] = att_s[c];
    adv[cb] = att_d[c];
  }
#pragma unroll
  for (int r = 0; r < 4; ++r) {
    int orow = row0 + w * 16 + kg * 4 + r;
    bool ok = orow < M;
    float sp = 0.f, dp = 0.f;
#pragma unroll
    for (int cb = 0; cb < 4; ++cb) {
      float v = acc[cb][r];
      if (ok) Cb[(size_t)orow * 64 + cb * 16 + rl] = f2bf(v);
      sp += v * asv[cb];
      dp += v * adv[cb];
    }
#pragma unroll
    for (int off = 1; off < 16; off <<= 1) {
      sp += __shfl_xor(sp, off, 64);
      dp += __shfl_xor(dp, off, 64);
    }
    if (ok && rl == 0) {
      as_out[orow] = sp;
      ad_out[orow] = dp;
    }
  }
}

// ---------------------------------------------------------------- layer 1 agg (chhalf-split, v7)
// Unit = (node, head, chhalf), one quarter-wave (16 lanes) each. bid%8 =
// head*2+chhalf -> XCD slice = contiguous 3.2 MB of h1t (< 4 MB L2) ->
// near-resident after warm; FETCH ~ compulsory. Phase 1 duplicated per chhalf
// (cheap exp). Phase 2: 4 edges/iter (e_off=sl>>2, cl=sl&3), 16B loads,
// 2-deep rotate pipeline.
__global__ __launch_bounds__(256) void agg1_kernel(const unsigned short* __restrict__ h1t,  // [8][M][32]
                                                   const float* __restrict__ as_t,          // [4][M]
                                                   const float* __restrict__ ad_t,          // [4][M]
                                                   const int* __restrict__ counts,
                                                   const unsigned short* __restrict__ col,
                                                   const float* __restrict__ b1,
                                                   unsigned short* __restrict__ x2b) {
  __shared__ int s_lds[16][64];
  __shared__ float p_lds[16][64];
  const int M = N_NODES;
  int bid = blockIdx.x;
  int hc = bid & 7;
  int head = hc >> 1, chh = hc & 1;
  int t = threadIdx.x;
  int qw = t >> 4;        // quarter-wave id 0..15
  int sl = t & 15;        // lane in quarter-wave
  int node = (bid >> 3) * 16 + qw;
  int cnt = min(counts[node], CAP);
  const unsigned short* cbase = col + (size_t)node * CAP;
  const float* as_h = as_t + (size_t)head * M;
  float adn = ad_t[(size_t)head * M + node];
  int nq = (cnt + 3) & ~3;  // cnt >= 1 -> nq >= 4
  // phase 1: rounds of 16, only as far as nq requires (pad p=0)
  float den = 0.f;
#pragma unroll
  for (int r = 0; r < 4; ++r) {
    if (r == 0 || r * 16 < nq) {
      int e = r * 16 + sl;
      int s = node;
      float p = 0.f;
      if (e < cnt) {
        s = cbase[e];
        p = __expf(lrelu(as_h[s] + adn));
      }
      s_lds[qw][e] = s;
      p_lds[qw][e] = p;
      den += p;
    }
  }
#pragma unroll
  for (int off = 1; off < 16; off <<= 1) den += __shfl_xor(den, off, 64);
  // phase 2
  int e_off = sl >> 2, cl = sl & 3;
  const unsigned short* hb = h1t + (size_t)hc * M * 32 + cl * 8;
  float acc[8] = {};
  int sa = s_lds[qw][e_off];
  float pa = p_lds[qw][e_off];
  bf16x8 va = *(const bf16x8*)(hb + (size_t)sa * 32);
  for (int j = 4; j < nq; j += 4) {
    int sb = s_lds[qw][j + e_off];
    float pb = p_lds[qw][j + e_off];
    bf16x8 vb = *(const bf16x8*)(hb + (size_t)sb * 32);
#pragma unroll
    for (int k = 0; k < 8; ++k) acc[k] += pa * bf2f((unsigned short)va[k]);
    va = vb; pa = pb;
  }
#pragma unroll
  for (int k = 0; k < 8; ++k) acc[k] += pa * bf2f((unsigned short)va[k]);
  // reduce across the 4 e_off groups (xor 4, 8 within quarter-wave)
#pragma unroll
  for (int k = 0; k < 8; ++k) {
    acc[k] += __shfl_xor(acc[k], 4, 64);
    acc[k] += __shfl_xor(acc[k], 8, 64);
  }
  if (e_off == 0) {
    float inv = 1.f / (den + 1e-16f);
    int ch = head * 64 + chh * 32 + cl * 8;
    float4 blo = *(const float4*)(b1 + ch);
    float4 bhi = *(const float4*)(b1 + ch + 4);
    float bb[8] = {blo.x, blo.y, blo.z, blo.w, bhi.x, bhi.y, bhi.z, bhi.w};
    bf16x8 o;
#pragma unroll
    for (int k = 0; k < 8; ++k) o[k] = (short)f2bf(fmaxf(acc[k] * inv + bb[k], 0.f));
    *(bf16x8*)(x2b + (size_t)node * 256 + ch) = o;
  }
}

// ---------------------------------------------------------------- layer 2 agg + head
__global__ __launch_bounds__(256) void agg2_final_kernel(const unsigned short* __restrict__ h2b,
                                                         const float* __restrict__ as,
                                                         const float* __restrict__ ad,
                                                         const int* __restrict__ counts,
                                                         const unsigned short* __restrict__ col,
                                                         const float* __restrict__ b2,
                                                         const float* __restrict__ Wout,
                                                         const float* __restrict__ bout,
                                                         float* __restrict__ out) {
  __shared__ int s_lds[4][64];
  __shared__ float p_lds[4][64];
  int t = threadIdx.x;
  int lane = t & 63, w = t >> 6;
  int node = blockIdx.x * 4 + w;
  if (node >= N_NODES) return;
  int cnt = min(counts[node], CAP);
  const unsigned short* cbase = col + (size_t)node * CAP;
  float adn = ad[node];
  int g = lane >> 4, sl = lane & 15;
  int s = node;
  float p = 0.f;
  if (lane < cnt) {
    s = cbase[lane];
    p = __expf(lrelu(as[s] + adn));
  }
  s_lds[w][lane] = s;
  p_lds[w][lane] = p;
  float den = p;
#pragma unroll
  for (int off = 1; off < 64; off <<= 1) den += __shfl_xor(den, off, 64);
  float acc[4] = {};
  int nq = (cnt + 7) & ~7;
  for (int j = 0; j < nq; j += 8) {
    int e0 = j + g, e1 = j + 4 + g;
    int s0 = s_lds[w][e0], s1 = s_lds[w][e1];
    float p0 = p_lds[w][e0], p1 = p_lds[w][e1];
    ushort4 v0 = *(const ushort4*)(h2b + (size_t)s0 * 64 + sl * 4);
    ushort4 v1 = *(const ushort4*)(h2b + (size_t)s1 * 64 + sl * 4);
    acc[0] += p0 * bf2f(v0.x) + p1 * bf2f(v1.x);
    acc[1] += p0 * bf2f(v0.y) + p1 * bf2f(v1.y);
    acc[2] += p0 * bf2f(v0.z) + p1 * bf2f(v1.z);
    acc[3] += p0 * bf2f(v0.w) + p1 * bf2f(v1.w);
  }
#pragma unroll
  for (int k = 0; k < 4; ++k) {
    acc[k] += __shfl_xor(acc[k], 16, 64);
    acc[k] += __shfl_xor(acc[k], 32, 64);
  }
  float inv = 1.f / (den + 1e-16f);
  int ch = sl * 4;
  float4 b4 = *(const float4*)(b2 + ch);
  float4 w4 = *(const float4*)(Wout + ch);
  float part = fmaxf(acc[0] * inv + b4.x, 0.f) * w4.x +
               fmaxf(acc[1] * inv + b4.y, 0.f) * w4.y +
               fmaxf(acc[2] * inv + b4.z, 0.f) * w4.z +
               fmaxf(acc[3] * inv + b4.w, 0.f) * w4.w;
#pragma unroll
  for (int off = 1; off < 16; off <<= 1) part += __shfl_xor(part, off, 64);
  if (lane == 0) out[node] = part + bout[0];
}

// ---------------------------------------------------------------- launch
extern "C" void kernel_launch(void* const* d_in, const int* in_sizes, int n_in,
                              void* d_out, int out_size, void* d_ws, size_t ws_size,
                              hipStream_t stream) {
  const float* x    = (const float*)d_in[0];
  const int*   ei   = (const int*)d_in[1];
  const float* W1   = (const float*)d_in[2];
  const float* as1w = (const float*)d_in[3];
  const float* ad1w = (const float*)d_in[4];
  const float* b1   = (const float*)d_in[5];
  const float* W2   = (const float*)d_in[6];
  const float* as2w = (const float*)d_in[7];
  const float* ad2w = (const float*)d_in[8];
  const float* b2   = (const float*)d_in[9];
  const float* Wout = (const float*)d_in[10];
  const float* bout = (const float*)d_in[11];
  float* out = (float*)d_out;

  const int* src = ei;
  const int* dst = ei + N_EDGES;

  char* ws = (char*)d_ws;
  size_t off = 0;
  auto alloc = [&](size_t bytes) -> char* {
    char* p = ws + off;
    off += (bytes + 255) & ~(size_t)255;
    return p;
  };
  int*            counts = (int*)alloc((size_t)N_NODES * 4);
  unsigned short* col    = (unsigned short*)alloc((size_t)N_NODES * CAP * 2);
  unsigned short* W1t    = (unsigned short*)alloc((size_t)256 * 128 * 2);
  unsigned short* W2t    = (unsigned short*)alloc((size_t)64 * 256 * 2);
  unsigned short* x2b    = (unsigned short*)alloc((size_t)N_NODES * 256 * 2);
  unsigned short* hbuf   = (unsigned short*)alloc((size_t)N_NODES * 256 * 2);
  float*          as1    = (float*)alloc((size_t)N_NODES * 4 * 4);  // as_t [4][M]
  float*          ad1    = (float*)alloc((size_t)N_NODES * 4 * 4);  // ad_t [4][M]
  float*          as2    = (float*)alloc((size_t)N_NODES * 4);
  float*          ad2    = (float*)alloc((size_t)N_NODES * 4);

  unsigned short* h1t = hbuf;  // [8][M][32] bf16, dead after agg1
  unsigned short* h2b = hbuf;  // [M][64]    bf16, written by gemm2 (after agg1)

  const int node_blocks4 = (N_NODES + 3) / 4;
  const int gemm_blocks = (N_NODES + 63) / 64;

  prep_kernel<<<(N_NODES + 255) / 256, 256, 0, stream>>>(W1, W2, W1t, W2t, counts);

  fused_kernel<<<FUSED_BLOCKS, 256, 0, stream>>>(src, dst, counts, col,
                                                 x, W1t, h1t, as1w, ad1w, as1, ad1);

  agg1_kernel<<<AGG1_BLOCKS, 256, 0, stream>>>(h1t, as1, ad1, counts, col, b1, x2b);

  gemm2_kernel<<<gemm_blocks, 256, 0, stream>>>(x2b, W2t, h2b, as2w, ad2w, as2, ad2);
  agg2_final_kernel<<<node_blocks4, 256, 0, stream>>>(h2b, as2, ad2, counts, col, b2,
                                                      Wout, bout, out);
}

// Round 16
// 152.249 us; speedup vs baseline: 1.1147x; 1.1147x over previous
//
#include <hip/hip_runtime.h>
#include <hip/hip_bf16.h>
#include <math.h>

#define N_NODES 50000
#define N_EDGES 800000
#define EE_TOTAL (N_EDGES + N_NODES)
#define CAP 64   // bucket capacity; in-degree ~ Binomial(800K, 1/50K), P(>64) ~ 1e-13
#define CST 16   // counter stride (ints): 1 counter per 64B line -> 16x atomic-line parallelism

#define GEMM1_BLOCKS ((N_NODES + 63) / 64)      // 782
#define SCAT_BLOCKS ((EE_TOTAL + 1023) / 1024)  // 831 (1024 edges/block, 4/thread)
#define FUSED_BLOCKS (GEMM1_BLOCKS + SCAT_BLOCKS)
#define AGG1_BLOCKS 25000  // 4 heads x 6250; bid%8 -> XCD affinity encodes head

typedef __attribute__((ext_vector_type(8))) short bf16x8;
typedef __attribute__((ext_vector_type(4))) float f32x4;

__device__ __forceinline__ float bf2f(unsigned short s) {
  return __uint_as_float((unsigned)s << 16);
}
__device__ __forceinline__ unsigned short f2bf(float f) {
  unsigned u = __float_as_uint(f);
  return (unsigned short)((u + 0x7FFFu + ((u >> 16) & 1u)) >> 16);  // RNE
}
__device__ __forceinline__ float lrelu(float e) { return e > 0.f ? e : 0.2f * e; }

// ---------------------------------------------------------------- prep
__global__ void prep_kernel(const float* __restrict__ W1, const float* __restrict__ W2,
                            unsigned short* __restrict__ W1t, unsigned short* __restrict__ W2t,
                            int* __restrict__ counts) {
  int i = blockIdx.x * blockDim.x + threadIdx.x;
  if (i < N_NODES * CST) counts[i] = 0;
  if (i < 256 * 128) W1t[i] = f2bf(W1[(i & 127) * 256 + (i >> 7)]);
  if (i < 64 * 256) W2t[i] = f2bf(W2[(i & 255) * 64 + (i >> 8)]);
}

// ---------------------------------------------------------------- fused scatter + GEMM1
__device__ __forceinline__ void scatter_body(int sid, int t,
                                             const int* __restrict__ src,
                                             const int* __restrict__ dst,
                                             int* __restrict__ counts,
                                             unsigned short* __restrict__ col) {
  int base = sid * 1024 + t * 4;
  int ss[4], dd[4];
#pragma unroll
  for (int k = 0; k < 4; ++k) {
    int i = base + k;
    if (i < N_EDGES) { ss[k] = src[i]; dd[k] = dst[i]; }
    else if (i < EE_TOTAL) { ss[k] = i - N_EDGES; dd[k] = ss[k]; }
    else { ss[k] = 0; dd[k] = -1; }
  }
#pragma unroll
  for (int k = 0; k < 4; ++k) {
    if (dd[k] >= 0) {
      int pos = atomicAdd(&counts[dd[k] * CST], 1);  // 1 counter / 64B line
      if (pos < CAP) col[(size_t)dd[k] * CAP + pos] = (unsigned short)ss[k];
    }
  }
}

__global__ __launch_bounds__(256) void fused_kernel(const int* __restrict__ src,
                                                    const int* __restrict__ dst,
                                                    int* __restrict__ counts,
                                                    unsigned short* __restrict__ col,
                                                    const float* __restrict__ A,           // x [M][128] f32
                                                    const unsigned short* __restrict__ Bt, // W1t [256][128]
                                                    unsigned short* __restrict__ Cb,       // h1b [M][256]
                                                    const float* __restrict__ att_s,
                                                    const float* __restrict__ att_d,
                                                    float* __restrict__ as_out,            // as_t [4][M]
                                                    float* __restrict__ ad_out) {          // ad_t [4][M]
  __shared__ unsigned short Bs[256 * 128];  // 64KB, XOR-swizzled (gemm blocks only)
  int b = blockIdx.x;
  int t = threadIdx.x;
  bool is_gemm;
  int id;
  if (b < 2 * GEMM1_BLOCKS) { is_gemm = (b & 1) == 0; id = b >> 1; }
  else { is_gemm = false; id = b - GEMM1_BLOCKS; }

  if (!is_gemm) {
    scatter_body(id, t, src, dst, counts, col);
    return;
  }

  const int M = N_NODES;
  int lane = t & 63, w = t >> 6;
  int row0 = id * 64;
#pragma unroll
  for (int i = 0; i < 16; ++i) {
    int idx = i * 256 + t;
    int n = idx >> 4;
    uint4 v = ((const uint4*)Bt)[idx];
    int byte = (idx * 16) ^ ((n & 7) << 4);
    *(uint4*)((char*)Bs + byte) = v;
  }
  __syncthreads();
  int rl = lane & 15, kg = lane >> 4;
  f32x4 acc[4][4] = {};
  for (int ks = 0; ks < 4; ++ks) {
    bf16x8 af[4], bfr[4];
#pragma unroll
    for (int rb = 0; rb < 4; ++rb) {
      int row = row0 + rb * 16 + rl;
      float4 v0 = make_float4(0.f, 0.f, 0.f, 0.f), v1 = v0;
      if (row < M) {
        const float* p = A + (size_t)row * 128 + ks * 32 + kg * 8;
        v0 = *(const float4*)p;
        v1 = *(const float4*)(p + 4);
      }
      bf16x8 a;
      a[0] = (short)f2bf(v0.x); a[1] = (short)f2bf(v0.y);
      a[2] = (short)f2bf(v0.z); a[3] = (short)f2bf(v0.w);
      a[4] = (short)f2bf(v1.x); a[5] = (short)f2bf(v1.y);
      a[6] = (short)f2bf(v1.z); a[7] = (short)f2bf(v1.w);
      af[rb] = a;
    }
#pragma unroll
    for (int cb = 0; cb < 4; ++cb) {
      int n = w * 64 + cb * 16 + rl;
      int byte = (n * 256 + ks * 64 + kg * 16) ^ ((n & 7) << 4);
      bfr[cb] = *(const bf16x8*)((char*)Bs + byte);
    }
#pragma unroll
    for (int rb = 0; rb < 4; ++rb)
#pragma unroll
      for (int cb = 0; cb < 4; ++cb)
        acc[rb][cb] = __builtin_amdgcn_mfma_f32_16x16x32_bf16(af[rb], bfr[cb], acc[rb][cb], 0, 0, 0);
  }
  float asv[4], adv[4];
#pragma unroll
  for (int cb = 0; cb < 4; ++cb) {
    int c = w * 64 + cb * 16 + rl;
    asv[cb] = att_s[c];
    adv[cb] = att_d[c];
  }
#pragma unroll
  for (int rb = 0; rb < 4; ++rb) {
#pragma unroll
    for (int r = 0; r < 4; ++r) {
      int row = row0 + rb * 16 + kg * 4 + r;
      bool ok = row < M;
      float sp = 0.f, dp = 0.f;
#pragma unroll
      for (int cb = 0; cb < 4; ++cb) {
        float v = acc[rb][cb][r];
        if (ok) Cb[(size_t)row * 256 + w * 64 + cb * 16 + rl] = f2bf(v);
        sp += v * asv[cb];
        dp += v * adv[cb];
      }
#pragma unroll
      for (int off = 1; off < 16; off <<= 1) {
        sp += __shfl_xor(sp, off, 64);
        dp += __shfl_xor(dp, off, 64);
      }
      if (ok && rl == 0) {
        as_out[w * M + row] = sp;  // transposed: head-major
        ad_out[w * M + row] = dp;
      }
    }
  }
}

// ---------------------------------------------------------------- GEMM2 (MFMA, LDS-staged)
__global__ __launch_bounds__(256) void gemm2_kernel(const unsigned short* __restrict__ A,   // x2b [M][256]
                                                    const unsigned short* __restrict__ Bt,  // [64][256]
                                                    unsigned short* __restrict__ Cb,        // [M][64]
                                                    const float* __restrict__ att_s,
                                                    const float* __restrict__ att_d,
                                                    float* __restrict__ as_out,             // [M]
                                                    float* __restrict__ ad_out) {
  __shared__ unsigned short Bs[64 * 256];  // 32KB
  const int M = N_NODES;
  int t = threadIdx.x;
  int lane = t & 63, w = t >> 6;
  int row0 = blockIdx.x * 64;
#pragma unroll
  for (int i = 0; i < 8; ++i) {
    int idx = i * 256 + t;
    int n = idx >> 5;
    uint4 v = ((const uint4*)Bt)[idx];
    int byte = (idx * 16) ^ ((n & 7) << 4);
    *(uint4*)((char*)Bs + byte) = v;
  }
  __syncthreads();
  int rl = lane & 15, kg = lane >> 4;
  int arow = row0 + w * 16 + rl;
  f32x4 acc[4] = {};
  for (int ks = 0; ks < 8; ++ks) {
    bf16x8 a = {};
    if (arow < M) a = *(const bf16x8*)(A + (size_t)arow * 256 + ks * 32 + kg * 8);
#pragma unroll
    for (int cb = 0; cb < 4; ++cb) {
      int n = cb * 16 + rl;
      int byte = (n * 512 + ks * 64 + kg * 16) ^ ((n & 7) << 4);
      bf16x8 bfrag = *(const bf16x8*)((char*)Bs + byte);
      acc[cb] = __builtin_amdgcn_mfma_f32_16x16x32_bf16(a, bfrag, acc[cb], 0, 0, 0);
    }
  }
  float asv[4], adv[4];
#pragma unroll
  for (int cb = 0; cb < 4; ++cb) {
    int c = cb * 16 + rl;
    asv[cb] = att_s[c];
    adv[cb] = att_d[c];
  }
#pragma unroll
  for (int r = 0; r < 4; ++r) {
    int orow = row0 + w * 16 + kg * 4 + r;
    bool ok = orow < M;
    float sp = 0.f, dp = 0.f;
#pragma unroll
    for (int cb = 0; cb < 4; ++cb) {
      float v = acc[cb][r];
      if (ok) Cb[(size_t)orow * 64 + cb * 16 + rl] = f2bf(v);
      sp += v * asv[cb];
      dp += v * adv[cb];
    }
#pragma unroll
    for (int off = 1; off < 16; off <<= 1) {
      sp += __shfl_xor(sp, off, 64);
      dp += __shfl_xor(dp, off, 64);
    }
    if (ok && rl == 0) {
      as_out[orow] = sp;
      ad_out[orow] = dp;
    }
  }
}

// ---------------------------------------------------------------- layer 1 agg (head-split, R13)
__global__ __launch_bounds__(256) void agg1_kernel(const unsigned short* __restrict__ h1b,
                                                   const float* __restrict__ as_t,  // [4][M]
                                                   const float* __restrict__ ad_t,  // [4][M]
                                                   const int* __restrict__ counts,
                                                   const unsigned short* __restrict__ col,
                                                   const float* __restrict__ b1,
                                                   unsigned short* __restrict__ x2b) {
  __shared__ int s_lds[8][64];
  __shared__ float p_lds[8][64];
  const int M = N_NODES;
  int bid = blockIdx.x;
  int head = (bid & 7) >> 1;
  int idx = (bid >> 3) * 2 + (bid & 1);  // [0, 6250)
  int t = threadIdx.x;
  int hw = t >> 5;        // half-wave id 0..7
  int sl = t & 31;        // lane in half-wave
  int node = idx * 8 + hw;
  int cnt = min(counts[node * CST], CAP);
  const unsigned short* cbase = col + (size_t)node * CAP;
  const float* as_h = as_t + (size_t)head * M;
  float adn = ad_t[(size_t)head * M + node];
  // phase 1: round 1 (always), round 2 only if cnt > 32
  float den = 0.f;
  {
    int e = sl;
    int s = node;
    float p = 0.f;
    if (e < cnt) {
      s = cbase[e];
      p = __expf(lrelu(as_h[s] + adn));
    }
    s_lds[hw][e] = s;
    p_lds[hw][e] = p;
    den += p;
  }
  if (cnt > 32) {
    int e = 32 + sl;
    int s = node;
    float p = 0.f;
    if (e < cnt) {
      s = cbase[e];
      p = __expf(lrelu(as_h[s] + adn));
    }
    s_lds[hw][e] = s;
    p_lds[hw][e] = p;
    den += p;
  }
#pragma unroll
  for (int off = 1; off < 32; off <<= 1) den += __shfl_xor(den, off, 64);
  // phase 2: 4 edges/iter, 2-deep rotate pipeline
  int e_off = sl >> 3, cl = sl & 7;
  const unsigned short* hb = h1b + head * 64 + cl * 8;
  float acc[8] = {};
  int nq = (cnt + 3) & ~3;  // cnt >= 1 -> nq >= 4
  int sa = s_lds[hw][e_off];
  float pa = p_lds[hw][e_off];
  bf16x8 va = *(const bf16x8*)(hb + (size_t)sa * 256);
  for (int j = 4; j < nq; j += 4) {
    int sb = s_lds[hw][j + e_off];
    float pb = p_lds[hw][j + e_off];
    bf16x8 vb = *(const bf16x8*)(hb + (size_t)sb * 256);
#pragma unroll
    for (int k = 0; k < 8; ++k) acc[k] += pa * bf2f((unsigned short)va[k]);
    va = vb; pa = pb;
  }
#pragma unroll
  for (int k = 0; k < 8; ++k) acc[k] += pa * bf2f((unsigned short)va[k]);
#pragma unroll
  for (int k = 0; k < 8; ++k) {
    acc[k] += __shfl_xor(acc[k], 8, 64);
    acc[k] += __shfl_xor(acc[k], 16, 64);
  }
  if (e_off == 0) {
    float inv = 1.f / (den + 1e-16f);
    int ch = head * 64 + cl * 8;
    float4 blo = *(const float4*)(b1 + ch);
    float4 bhi = *(const float4*)(b1 + ch + 4);
    float bb[8] = {blo.x, blo.y, blo.z, blo.w, bhi.x, bhi.y, bhi.z, bhi.w};
    bf16x8 o;
#pragma unroll
    for (int k = 0; k < 8; ++k) o[k] = (short)f2bf(fmaxf(acc[k] * inv + bb[k], 0.f));
    *(bf16x8*)(x2b + (size_t)node * 256 + ch) = o;
  }
}

// ---------------------------------------------------------------- layer 2 agg + head
__global__ __launch_bounds__(256) void agg2_final_kernel(const unsigned short* __restrict__ h2b,
                                                         const float* __restrict__ as,
                                                         const float* __restrict__ ad,
                                                         const int* __restrict__ counts,
                                                         const unsigned short* __restrict__ col,
                                                         const float* __restrict__ b2,
                                                         const float* __restrict__ Wout,
                                                         const float* __restrict__ bout,
                                                         float* __restrict__ out) {
  __shared__ int s_lds[4][64];
  __shared__ float p_lds[4][64];
  int t = threadIdx.x;
  int lane = t & 63, w = t >> 6;
  int node = blockIdx.x * 4 + w;
  if (node >= N_NODES) return;
  int cnt = min(counts[node * CST], CAP);
  const unsigned short* cbase = col + (size_t)node * CAP;
  float adn = ad[node];
  int g = lane >> 4, sl = lane & 15;
  int s = node;
  float p = 0.f;
  if (lane < cnt) {
    s = cbase[lane];
    p = __expf(lrelu(as[s] + adn));
  }
  s_lds[w][lane] = s;
  p_lds[w][lane] = p;
  float den = p;
#pragma unroll
  for (int off = 1; off < 64; off <<= 1) den += __shfl_xor(den, off, 64);
  float acc[4] = {};
  int nq = (cnt + 7) & ~7;
  for (int j = 0; j < nq; j += 8) {
    int e0 = j + g, e1 = j + 4 + g;
    int s0 = s_lds[w][e0], s1 = s_lds[w][e1];
    float p0 = p_lds[w][e0], p1 = p_lds[w][e1];
    ushort4 v0 = *(const ushort4*)(h2b + (size_t)s0 * 64 + sl * 4);
    ushort4 v1 = *(const ushort4*)(h2b + (size_t)s1 * 64 + sl * 4);
    acc[0] += p0 * bf2f(v0.x) + p1 * bf2f(v1.x);
    acc[1] += p0 * bf2f(v0.y) + p1 * bf2f(v1.y);
    acc[2] += p0 * bf2f(v0.z) + p1 * bf2f(v1.z);
    acc[3] += p0 * bf2f(v0.w) + p1 * bf2f(v1.w);
  }
#pragma unroll
  for (int k = 0; k < 4; ++k) {
    acc[k] += __shfl_xor(acc[k], 16, 64);
    acc[k] += __shfl_xor(acc[k], 32, 64);
  }
  float inv = 1.f / (den + 1e-16f);
  int ch = sl * 4;
  float4 b4 = *(const float4*)(b2 + ch);
  float4 w4 = *(const float4*)(Wout + ch);
  float part = fmaxf(acc[0] * inv + b4.x, 0.f) * w4.x +
               fmaxf(acc[1] * inv + b4.y, 0.f) * w4.y +
               fmaxf(acc[2] * inv + b4.z, 0.f) * w4.z +
               fmaxf(acc[3] * inv + b4.w, 0.f) * w4.w;
#pragma unroll
  for (int off = 1; off < 16; off <<= 1) part += __shfl_xor(part, off, 64);
  if (lane == 0) out[node] = part + bout[0];
}

// ---------------------------------------------------------------- launch
extern "C" void kernel_launch(void* const* d_in, const int* in_sizes, int n_in,
                              void* d_out, int out_size, void* d_ws, size_t ws_size,
                              hipStream_t stream) {
  const float* x    = (const float*)d_in[0];
  const int*   ei   = (const int*)d_in[1];
  const float* W1   = (const float*)d_in[2];
  const float* as1w = (const float*)d_in[3];
  const float* ad1w = (const float*)d_in[4];
  const float* b1   = (const float*)d_in[5];
  const float* W2   = (const float*)d_in[6];
  const float* as2w = (const float*)d_in[7];
  const float* ad2w = (const float*)d_in[8];
  const float* b2   = (const float*)d_in[9];
  const float* Wout = (const float*)d_in[10];
  const float* bout = (const float*)d_in[11];
  float* out = (float*)d_out;

  const int* src = ei;
  const int* dst = ei + N_EDGES;

  char* ws = (char*)d_ws;
  size_t off = 0;
  auto alloc = [&](size_t bytes) -> char* {
    char* p = ws + off;
    off += (bytes + 255) & ~(size_t)255;
    return p;
  };
  int*            counts = (int*)alloc((size_t)N_NODES * CST * 4);  // padded: 1/64B line
  unsigned short* col    = (unsigned short*)alloc((size_t)N_NODES * CAP * 2);
  unsigned short* W1t    = (unsigned short*)alloc((size_t)256 * 128 * 2);
  unsigned short* W2t    = (unsigned short*)alloc((size_t)64 * 256 * 2);
  unsigned short* x2b    = (unsigned short*)alloc((size_t)N_NODES * 256 * 2);
  unsigned short* hbuf   = (unsigned short*)alloc((size_t)N_NODES * 256 * 2);
  float*          as1    = (float*)alloc((size_t)N_NODES * 4 * 4);  // as_t [4][M]
  float*          ad1    = (float*)alloc((size_t)N_NODES * 4 * 4);  // ad_t [4][M]
  float*          as2    = (float*)alloc((size_t)N_NODES * 4);
  float*          ad2    = (float*)alloc((size_t)N_NODES * 4);

  unsigned short* h1b = hbuf;  // [M][256] bf16, dead after agg1
  unsigned short* h2b = hbuf;  // [M][64]  bf16, written by gemm2 (after agg1)

  const int node_blocks4 = (N_NODES + 3) / 4;
  const int gemm_blocks = (N_NODES + 63) / 64;

  prep_kernel<<<(N_NODES * CST + 255) / 256, 256, 0, stream>>>(W1, W2, W1t, W2t, counts);

  fused_kernel<<<FUSED_BLOCKS, 256, 0, stream>>>(src, dst, counts, col,
                                                 x, W1t, h1b, as1w, ad1w, as1, ad1);

  agg1_kernel<<<AGG1_BLOCKS, 256, 0, stream>>>(h1b, as1, ad1, counts, col, b1, x2b);

  gemm2_kernel<<<gemm_blocks, 256, 0, stream>>>(x2b, W2t, h2b, as2w, ad2w, as2, ad2);
  agg2_final_kernel<<<node_blocks4, 256, 0, stream>>>(h2b, as2, ad2, counts, col, b2,
                                                      Wout, bout, out);
}